// Round 9
// baseline (150.394 us; speedup 1.0000x reference)
//
#include <hip/hip_runtime.h>
#include <hip/hip_bf16.h>

// Problem constants
static constexpr int NN = 512, CC = 1000, PP = 256, ORD = 127;

// Workspace layout (bytes) — identical to R5 (proven to run)
static constexpr size_t OFF_TEMPT  = 0;                       // PP*CC f32
static constexpr size_t OFF_KAPPA  = (size_t)PP * CC * 4;     // CC f32
static constexpr size_t OFF_LOGC   = OFF_KAPPA + 8192;        // CC f64
static constexpr size_t OFF_LOGITS = OFF_LOGC + 8192;         // NN*CC f32

// Miller backward recurrence exactly as the reference (seed (1,0) at i=2*ORD,
// down to i=1). Domain k in [~1100, 1e5+20]: Itilde_0 <= ~e^31, no f64
// overflow, so the reference's global rescale branch never fires.
__device__ inline double miller_e0(double k) {
    const double inv = 1.0 / k;
    double In = 1.0, In1 = 0.0;
    double c2 = 2.0 * (2 * ORD);          // 508
    for (int it = 0; it < ORD; ++it) {    // i = 254 .. 128
        double t = fma(c2 * inv, In, In1);
        In1 = In; In = t; c2 -= 2.0;
    }
    double E0 = In;                       // Itilde_127
    for (int it = 0; it < ORD; ++it) {    // i = 127 .. 1
        double t = fma(c2 * inv, In, In1);
        In1 = In; In = t; c2 -= 2.0;
    }
    // log(i0e(k)) asymptotic series; k >= ~1000 -> rel err ~1e-13
    double x = 0.125 * inv;               // 1/(8k)
    double pser = x * (1.0 + x * (4.5 + x * (37.5 + x * 459.375)));
    double li0e = log1p(pser) - 0.5 * log(6.283185307179586 * k);
    return li0e + log(E0 / In);
}

// Kernel 1: per-class stats -> temp^T ([a][c] f32) and kappa_c (identical to R5)
__global__ __launch_bounds__(256) void k_stats(
    const float* __restrict__ feats, const unsigned* __restrict__ A,
    const unsigned* __restrict__ B, const float* __restrict__ Ave,
    const float* __restrict__ Amount, float* __restrict__ tempT,
    float* __restrict__ kappa_out)
{
    __shared__ int           lab_s[NN];
    __shared__ unsigned char msk_s[NN];
    __shared__ float red4[4];
    __shared__ int s_fl[2];
    const int c = blockIdx.x;
    const int tid = threadIdx.x;

    if (tid < 2) s_fl[tid] = 0;
    __syncthreads();
    int f0 = 0, f1 = 0;
    for (int w = tid; w < NN; w += 256) {
        if (A[w] > 1u) f0 = 1;
        if (B[w] > 1u) f1 = 1;
    }
    if (f0) atomicOr(&s_fl[0], 1);
    if (f1) atomicOr(&s_fl[1], 1);
    __syncthreads();
    const bool a_is_lab = s_fl[0] ? true : (s_fl[1] ? false : true);
    const unsigned* LAB = a_is_lab ? A : B;
    const unsigned* MSK = a_is_lab ? B : A;

    for (int n = tid; n < NN; n += 256) {
        lab_s[n] = (int)LAB[n];
        msk_s[n] = (unsigned char)(MSK[n] != 0u);
    }
    __syncthreads();

    float sum = 0.f, cnt = 0.f;
    for (int n = 0; n < NN; ++n) {
        if (msk_s[n] && lab_s[n] == c) { sum += feats[n * PP + tid]; cnt += 1.f; }
    }
    float amount = Amount[c];
    float w = cnt / (cnt + amount);          // 0/0 -> NaN when cnt==0, Amount==0
    if (isnan(w)) w = 0.f;
    float denom = (cnt == 0.f) ? 1.f : cnt;
    float ave = sum / denom;
    float av_new = Ave[c * PP + tid] * (1.f - w) + ave * w;

    float ss = av_new * av_new;
    for (int off = 32; off > 0; off >>= 1) ss += __shfl_down(ss, off);
    if ((tid & 63) == 0) red4[tid >> 6] = ss;
    __syncthreads();
    float tot = red4[0] + red4[1] + red4[2] + red4[3];

    float R = sqrtf(tot);
    float kf = 256.0f * R / (1.0f - R * R);
    if (kf > 1e5f || kf < 0.0f) kf = 1e5f;   // matches reference clamp
    float mu = av_new / fmaxf(R, 1e-12f);
    tempT[tid * CC + c] = kf * mu;           // f32 rounding matches reference temp
    if (tid == 0) kappa_out[c] = kf;
}

// Kernel 2: logc per class (f64, identical to R5)
__global__ __launch_bounds__(256) void k_logc(
    const float* __restrict__ kappa, double* __restrict__ logc)
{
    int c = blockIdx.x * 256 + threadIdx.x;
    if (c >= CC) return;
    double k = (double)kappa[c];
    logc[c] = miller_e0(k) + k - 127.0 * log(k + 1e-20);
}

// Kernel 3: logits -> f32 ws (identical to R5)
__global__ __launch_bounds__(256) void k_logits(
    const float* __restrict__ feats, const float* __restrict__ tempT,
    const double* __restrict__ logc, float* __restrict__ logits)
{
    __shared__ float f_s[PP];
    const int n = blockIdx.y;
    const int tid = threadIdx.x;
    const int c = blockIdx.x * 256 + tid;
    f_s[tid] = feats[n * PP + tid];
    __syncthreads();
    if (c >= CC) return;

    double acc = 0.0;
    #pragma unroll 8
    for (int a = 0; a < PP; ++a) {
        float t = tempT[a * CC + c] + f_s[a];  // f32, matches reference t
        acc = fma((double)t, (double)t, acc);
    }
    double k = (double)(float)sqrt(acc);  // f32-round like reference kappa_new
    double e0 = miller_e0(k);
    double lg = e0 + k - 127.0 * log(k + 1e-20) - logc[c];
    logits[n * CC + c] = (float)lg;
}

// Kernel 4: row-normalize -> FLOAT32 output (the fix: d_out is float*, since
// the reference's output dtype is float32 — "bfloat16 -> __hip_bfloat16*,
// else float*". Writing bf16 here was the sole bug behind rounds 0-8.)
__global__ __launch_bounds__(256) void k_norm(
    const float* __restrict__ logits, float* __restrict__ out)
{
    __shared__ double red4[4];
    const int n = blockIdx.x;
    const int tid = threadIdx.x;
    float v[4];
    double ss = 0.0;
    #pragma unroll
    for (int q = 0; q < 4; ++q) {
        int c = tid + q * 256;
        v[q] = (c < CC) ? logits[n * CC + c] : 0.f;
        ss += (double)v[q] * (double)v[q];
    }
    for (int off = 32; off > 0; off >>= 1) ss += __shfl_down(ss, off);
    if ((tid & 63) == 0) red4[tid >> 6] = ss;
    __syncthreads();
    double tot = red4[0] + red4[1] + red4[2] + red4[3];
    float inv = 1.0f / fmaxf((float)sqrt(tot), 1e-12f);
    #pragma unroll
    for (int q = 0; q < 4; ++q) {
        int c = tid + q * 256;
        if (c < CC) out[n * CC + c] = v[q] * inv;
    }
}

extern "C" void kernel_launch(void* const* d_in, const int* in_sizes, int n_in,
                              void* d_out, int out_size, void* d_ws, size_t ws_size,
                              hipStream_t stream) {
    // Slot identification by element count (features=131072, Ave=256000,
    // Amount=1000, labels/mask=512 each; the two 512s keep slot order and are
    // disambiguated on-device by value: labels contain values > 1).
    int i_feat = -1, i_ave = -1, i_amt = -1, i5a = -1, i5b = -1;
    for (int i = 0; i < n_in; ++i) {
        int s = in_sizes[i];
        if      (s == NN * PP) i_feat = i;
        else if (s == CC * PP) i_ave  = i;
        else if (s == CC)      i_amt  = i;
        else if (s == NN)      { if (i5a < 0) i5a = i; else i5b = i; }
    }
    if (i_feat < 0 || i_ave < 0 || i_amt < 0 || i5a < 0 || i5b < 0) {
        i_feat = 0; i5a = 1; i5b = 2; i_ave = 3; i_amt = 4;  // documented order
    }
    const float*    feats  = (const float*)d_in[i_feat];
    const unsigned* bufA   = (const unsigned*)d_in[i5a];
    const unsigned* bufB   = (const unsigned*)d_in[i5b];
    const float*    Ave    = (const float*)d_in[i_ave];
    const float*    Amount = (const float*)d_in[i_amt];

    char* ws = (char*)d_ws;
    float*  tempT  = (float*)(ws + OFF_TEMPT);
    float*  kappa  = (float*)(ws + OFF_KAPPA);
    double* logc   = (double*)(ws + OFF_LOGC);
    float*  logits = (float*)(ws + OFF_LOGITS);
    float*  out    = (float*)d_out;                          // FLOAT32 output

    k_stats<<<dim3(CC), dim3(256), 0, stream>>>(feats, bufA, bufB, Ave, Amount,
                                                tempT, kappa);
    k_logc<<<dim3((CC + 255) / 256), dim3(256), 0, stream>>>(kappa, logc);
    k_logits<<<dim3((CC + 255) / 256, NN), dim3(256), 0, stream>>>(feats, tempT,
                                                                   logc, logits);
    k_norm<<<dim3(NN), dim3(256), 0, stream>>>(logits, out);
}

// Round 10
// 118.795 us; speedup vs baseline: 1.2660x; 1.2660x over previous
//
#include <hip/hip_runtime.h>
#include <hip/hip_bf16.h>

// Problem constants
static constexpr int NN = 512, CC = 1000, PP = 256, ORD = 127;

// Workspace layout (bytes). ACCUM/CNT alias the LOGITS region (dead until k_main).
static constexpr size_t OFF_TEMPT  = 0;                       // PP*CC f32 (1,024,000)
static constexpr size_t OFF_KAPPA  = 1024000;                 // CC f32   (4096 pad)
static constexpr size_t OFF_LOGC   = 1028096;                 // CC f64   (8192)
static constexpr size_t OFF_T2     = 1036288;                 // CC f64   (8192)
static constexpr size_t OFF_F2     = 1044480;                 // NN f64   (4096)
static constexpr size_t OFF_LOGITS = 1048576;                 // NN*CC f32 (2,048,000)
static constexpr size_t OFF_ACCUM  = OFF_LOGITS;              // CC*PP f32 (alias)
static constexpr size_t OFF_CNT    = OFF_LOGITS + 1024000;    // CC i32   (alias)

// Miller backward recurrence exactly as the reference (seed (1,0) at i=2*ORD,
// down to i=1). Domain k in [~1100, 1e5+20]: no f64 overflow, the reference's
// rescale branch never fires. (Scalar version, used for logc.)
__device__ inline double miller_e0(double k) {
    const double inv = 1.0 / k;
    double In = 1.0, In1 = 0.0;
    double c2 = 2.0 * (2 * ORD);          // 508
    for (int it = 0; it < ORD; ++it) {    // i = 254 .. 128
        double t = fma(c2 * inv, In, In1);
        In1 = In; In = t; c2 -= 2.0;
    }
    double E0 = In;                       // Itilde_127
    for (int it = 0; it < ORD; ++it) {    // i = 127 .. 1
        double t = fma(c2 * inv, In, In1);
        In1 = In; In = t; c2 -= 2.0;
    }
    double x = 0.125 * inv;               // 1/(8k)
    double pser = x * (1.0 + x * (4.5 + x * (37.5 + x * 459.375)));
    double li0e = log1p(pser) - 0.5 * log(6.283185307179586 * k);
    return li0e + log(E0 / In);
}

// Kernel A: zero class accumulators
__global__ __launch_bounds__(256) void k_zero(float* __restrict__ accum,
                                              int* __restrict__ cnt)
{
    int i = blockIdx.x * 256 + threadIdx.x;
    if (i < CC * PP) accum[i] = 0.f;
    if (i < CC) cnt[i] = 0;
}

// Kernel B: one block per sample — per-row sumsq (F2) + masked scatter into class
// accumulators. Labels/mask roles detected by value (labels contain >1).
__global__ __launch_bounds__(256) void k_scatter(
    const float* __restrict__ feats, const unsigned* __restrict__ A,
    const unsigned* __restrict__ B, float* __restrict__ accum,
    int* __restrict__ cnt, double* __restrict__ F2)
{
    __shared__ int s_fl[2];
    __shared__ double red4[4];
    const int n = blockIdx.x, tid = threadIdx.x;
    if (tid < 2) s_fl[tid] = 0;
    __syncthreads();
    int f0 = 0, f1 = 0;
    for (int w = tid; w < NN; w += 256) {
        if (A[w] > 1u) f0 = 1;
        if (B[w] > 1u) f1 = 1;
    }
    if (f0) atomicOr(&s_fl[0], 1);
    if (f1) atomicOr(&s_fl[1], 1);
    __syncthreads();
    const bool a_is_lab = s_fl[0] ? true : (s_fl[1] ? false : true);
    const unsigned* LAB = a_is_lab ? A : B;
    const unsigned* MSK = a_is_lab ? B : A;
    const int  lab = (int)LAB[n];
    const bool mk  = (MSK[n] != 0u);

    float v = feats[n * PP + tid];
    double ss = (double)v * (double)v;
    for (int off = 32; off > 0; off >>= 1) ss += __shfl_down(ss, off);
    if ((tid & 63) == 0) red4[tid >> 6] = ss;
    __syncthreads();
    if (tid == 0) F2[n] = red4[0] + red4[1] + red4[2] + red4[3];

    if (mk) {
        atomicAdd(&accum[lab * PP + tid], v);
        if (tid == 0) atomicAdd(&cnt[lab], 1);
    }
}

// Kernel C: per-class finalize -> temp^T ([a][c] f32), kappa_c, T2_c = sum temp^2 (f64)
__global__ __launch_bounds__(256) void k_class(
    const float* __restrict__ accum, const int* __restrict__ cnt,
    const float* __restrict__ Ave, const float* __restrict__ Amount,
    float* __restrict__ tempT, float* __restrict__ kappa_out,
    double* __restrict__ T2)
{
    __shared__ float  red4[4];
    __shared__ double redd[4];
    const int c = blockIdx.x, tid = threadIdx.x;
    float cntf   = (float)cnt[c];
    float amount = Amount[c];
    float w = cntf / (cntf + amount);        // 0/0 -> NaN when cnt==0, Amount==0
    if (isnan(w)) w = 0.f;
    float denom = (cntf == 0.f) ? 1.f : cntf;
    float ave = accum[c * PP + tid] / denom;
    float av_new = Ave[c * PP + tid] * (1.f - w) + ave * w;

    float ss = av_new * av_new;
    for (int off = 32; off > 0; off >>= 1) ss += __shfl_down(ss, off);
    if ((tid & 63) == 0) red4[tid >> 6] = ss;
    __syncthreads();
    float tot = red4[0] + red4[1] + red4[2] + red4[3];

    float R = sqrtf(tot);
    float kf = 256.0f * R / (1.0f - R * R);
    if (kf > 1e5f || kf < 0.0f) kf = 1e5f;   // matches reference clamp
    float mu = av_new / fmaxf(R, 1e-12f);
    float tv = kf * mu;                      // f32 rounding matches reference temp
    tempT[tid * CC + c] = tv;

    double ts = (double)tv * (double)tv;
    for (int off = 32; off > 0; off >>= 1) ts += __shfl_down(ts, off);
    if ((tid & 63) == 0) redd[tid >> 6] = ts;
    __syncthreads();
    if (tid == 0) { kappa_out[c] = kf; T2[c] = redd[0] + redd[1] + redd[2] + redd[3]; }
}

// Kernel D: logc per class (f64)
__global__ __launch_bounds__(256) void k_logc(
    const float* __restrict__ kappa, double* __restrict__ logc)
{
    int c = blockIdx.x * 256 + threadIdx.x;
    if (c >= CC) return;
    double k = (double)kappa[c];
    logc[c] = miller_e0(k) + k - 127.0 * log(k + 1e-20);
}

// Kernel E: main. grid (4 c-tiles, 128 n-tiles of 4). Per thread: one c, 4 n's.
// Phase 1: f32 cross-dot D = temp_c . f_n  (LDS-broadcast f, coalesced tempT).
// Phase 2: k = sqrt(T2 + 2D + F2) f32-rounded, then 4 interleaved Miller chains.
__global__ __launch_bounds__(256) void k_main(
    const float* __restrict__ feats, const float* __restrict__ tempT,
    const double* __restrict__ T2, const double* __restrict__ F2,
    const double* __restrict__ logc, float* __restrict__ logits)
{
    __shared__ float f_s[4][PP];
    const int tid = threadIdx.x;
    const int n0  = blockIdx.y * 4;
    const int c   = blockIdx.x * 256 + tid;
    #pragma unroll
    for (int j = 0; j < 4; ++j)
        f_s[j][tid] = feats[(n0 + j) * PP + tid];
    __syncthreads();
    const bool act = (c < CC);

    float a0 = 0.f, a1 = 0.f, a2 = 0.f, a3 = 0.f;
    if (act) {
        #pragma unroll 4
        for (int a = 0; a < PP; ++a) {
            float tv = tempT[a * CC + c];
            a0 = fmaf(tv, f_s[0][a], a0);
            a1 = fmaf(tv, f_s[1][a], a1);
            a2 = fmaf(tv, f_s[2][a], a2);
            a3 = fmaf(tv, f_s[3][a], a3);
        }
    }
    double accs[4] = {(double)a0, (double)a1, (double)a2, (double)a3};
    double t2c = act ? T2[c] : 1.0e6;
    double kd[4], inv[4], In[4], In1[4], E0[4];
    #pragma unroll
    for (int j = 0; j < 4; ++j) {
        double kk = act ? (t2c + 2.0 * accs[j] + F2[n0 + j]) : 1.0e6;
        kd[j]  = (double)(float)sqrt(kk);   // f32-round like reference kappa_new
        inv[j] = 1.0 / kd[j];
        In[j] = 1.0; In1[j] = 0.0;
    }
    double c2 = 508.0;
    for (int it = 0; it < ORD; ++it) {      // i = 254 .. 128
        #pragma unroll
        for (int j = 0; j < 4; ++j) {
            double t = fma(c2 * inv[j], In[j], In1[j]);
            In1[j] = In[j]; In[j] = t;
        }
        c2 -= 2.0;
    }
    #pragma unroll
    for (int j = 0; j < 4; ++j) E0[j] = In[j];
    for (int it = 0; it < ORD; ++it) {      // i = 127 .. 1
        #pragma unroll
        for (int j = 0; j < 4; ++j) {
            double t = fma(c2 * inv[j], In[j], In1[j]);
            In1[j] = In[j]; In[j] = t;
        }
        c2 -= 2.0;
    }
    if (!act) return;
    double lgc = logc[c];
    #pragma unroll
    for (int j = 0; j < 4; ++j) {
        double x = 0.125 * inv[j];
        double pser = x * (1.0 + x * (4.5 + x * (37.5 + x * 459.375)));
        double li0e = log1p(pser) - 0.5 * log(6.283185307179586 * kd[j]);
        double e0 = li0e + log(E0[j] / In[j]);
        double lg = e0 + kd[j] - 127.0 * log(kd[j] + 1e-20) - lgc;
        logits[(n0 + j) * CC + c] = (float)lg;
    }
}

// Kernel F: row-normalize -> f32 output
__global__ __launch_bounds__(256) void k_norm(
    const float* __restrict__ logits, float* __restrict__ out)
{
    __shared__ double red4[4];
    const int n = blockIdx.x;
    const int tid = threadIdx.x;
    float v[4];
    double ss = 0.0;
    #pragma unroll
    for (int q = 0; q < 4; ++q) {
        int c = tid + q * 256;
        v[q] = (c < CC) ? logits[n * CC + c] : 0.f;
        ss += (double)v[q] * (double)v[q];
    }
    for (int off = 32; off > 0; off >>= 1) ss += __shfl_down(ss, off);
    if ((tid & 63) == 0) red4[tid >> 6] = ss;
    __syncthreads();
    double tot = red4[0] + red4[1] + red4[2] + red4[3];
    float inv = 1.0f / fmaxf((float)sqrt(tot), 1e-12f);
    #pragma unroll
    for (int q = 0; q < 4; ++q) {
        int c = tid + q * 256;
        if (c < CC) out[n * CC + c] = v[q] * inv;
    }
}

extern "C" void kernel_launch(void* const* d_in, const int* in_sizes, int n_in,
                              void* d_out, int out_size, void* d_ws, size_t ws_size,
                              hipStream_t stream) {
    int i_feat = -1, i_ave = -1, i_amt = -1, i5a = -1, i5b = -1;
    for (int i = 0; i < n_in; ++i) {
        int s = in_sizes[i];
        if      (s == NN * PP) i_feat = i;
        else if (s == CC * PP) i_ave  = i;
        else if (s == CC)      i_amt  = i;
        else if (s == NN)      { if (i5a < 0) i5a = i; else i5b = i; }
    }
    if (i_feat < 0 || i_ave < 0 || i_amt < 0 || i5a < 0 || i5b < 0) {
        i_feat = 0; i5a = 1; i5b = 2; i_ave = 3; i_amt = 4;  // documented order
    }
    const float*    feats  = (const float*)d_in[i_feat];
    const unsigned* bufA   = (const unsigned*)d_in[i5a];
    const unsigned* bufB   = (const unsigned*)d_in[i5b];
    const float*    Ave    = (const float*)d_in[i_ave];
    const float*    Amount = (const float*)d_in[i_amt];

    char* ws = (char*)d_ws;
    float*  tempT  = (float*)(ws + OFF_TEMPT);
    float*  kappa  = (float*)(ws + OFF_KAPPA);
    double* logc   = (double*)(ws + OFF_LOGC);
    double* T2     = (double*)(ws + OFF_T2);
    double* F2     = (double*)(ws + OFF_F2);
    float*  logits = (float*)(ws + OFF_LOGITS);
    float*  accum  = (float*)(ws + OFF_ACCUM);   // aliases logits (dead then)
    int*    cnt    = (int*)(ws + OFF_CNT);
    float*  out    = (float*)d_out;

    k_zero<<<dim3((CC * PP + 255) / 256), dim3(256), 0, stream>>>(accum, cnt);
    k_scatter<<<dim3(NN), dim3(256), 0, stream>>>(feats, bufA, bufB, accum, cnt, F2);
    k_class<<<dim3(CC), dim3(256), 0, stream>>>(accum, cnt, Ave, Amount,
                                                tempT, kappa, T2);
    k_logc<<<dim3((CC + 255) / 256), dim3(256), 0, stream>>>(kappa, logc);
    k_main<<<dim3(4, NN / 4), dim3(256), 0, stream>>>(feats, tempT, T2, F2,
                                                      logc, logits);
    k_norm<<<dim3(NN), dim3(256), 0, stream>>>(logits, out);
}

// Round 11
// 108.927 us; speedup vs baseline: 1.3807x; 1.0906x over previous
//
#include <hip/hip_runtime.h>

// Problem constants
static constexpr int NN = 512, CC = 1000, PP = 256, ORD = 127;

// Workspace layout (bytes). ACCUM/CNT alias the LOGITS region (dead until k_main).
static constexpr size_t OFF_TEMPT  = 0;                       // PP*CC f32 (1,024,000)
static constexpr size_t OFF_KAPPA  = 1024000;                 // CC f32
static constexpr size_t OFF_LOGC   = 1028096;                 // CC f64
static constexpr size_t OFF_T2     = 1036288;                 // CC f64
static constexpr size_t OFF_F2     = 1044480;                 // NN f64
static constexpr size_t OFF_LOGITS = 1048576;                 // NN*CC f32 (2,048,000)
static constexpr size_t OFF_ACCUM  = OFF_LOGITS;              // CC*PP f32 (alias)
static constexpr size_t OFF_CNT    = OFF_LOGITS + 1024000;    // CC i32   (alias)

// Kernel A: one block per sample — per-row sumsq (F2) + masked scatter into class
// accumulators. Labels/mask roles detected by value (labels contain >1).
__global__ __launch_bounds__(256) void k_scatter(
    const float* __restrict__ feats, const unsigned* __restrict__ A,
    const unsigned* __restrict__ B, float* __restrict__ accum,
    int* __restrict__ cnt, double* __restrict__ F2)
{
    __shared__ int s_fl[2];
    __shared__ double red4[4];
    const int n = blockIdx.x, tid = threadIdx.x;
    if (tid < 2) s_fl[tid] = 0;
    __syncthreads();
    int f0 = 0, f1 = 0;
    for (int w = tid; w < NN; w += 256) {
        if (A[w] > 1u) f0 = 1;
        if (B[w] > 1u) f1 = 1;
    }
    if (f0) atomicOr(&s_fl[0], 1);
    if (f1) atomicOr(&s_fl[1], 1);
    __syncthreads();
    const bool a_is_lab = s_fl[0] ? true : (s_fl[1] ? false : true);
    const unsigned* LAB = a_is_lab ? A : B;
    const unsigned* MSK = a_is_lab ? B : A;
    const int  lab = (int)LAB[n];
    const bool mk  = (MSK[n] != 0u);

    float v = feats[n * PP + tid];
    double ss = (double)v * (double)v;
    for (int off = 32; off > 0; off >>= 1) ss += __shfl_down(ss, off);
    if ((tid & 63) == 0) red4[tid >> 6] = ss;
    __syncthreads();
    if (tid == 0) F2[n] = red4[0] + red4[1] + red4[2] + red4[3];

    if (mk) {
        atomicAdd(&accum[lab * PP + tid], v);
        if (tid == 0) atomicAdd(&cnt[lab], 1);
    }
}

// Kernel B: per-class finalize -> temp^T ([a][c] f32), kappa_c, T2_c (f64),
// plus FUSED logc computation (f32 Miller chain at tid 0; final assembly f64).
__global__ __launch_bounds__(256) void k_class(
    const float* __restrict__ accum, const int* __restrict__ cnt,
    const float* __restrict__ Ave, const float* __restrict__ Amount,
    float* __restrict__ tempT, float* __restrict__ kappa_out,
    double* __restrict__ T2, double* __restrict__ logc)
{
    __shared__ float  red4[4];
    __shared__ double redd[4];
    const int c = blockIdx.x, tid = threadIdx.x;
    float cntf   = (float)cnt[c];
    float amount = Amount[c];
    float w = cntf / (cntf + amount);        // 0/0 -> NaN when cnt==0, Amount==0
    if (isnan(w)) w = 0.f;
    float denom = (cntf == 0.f) ? 1.f : cntf;
    float ave = accum[c * PP + tid] / denom;
    float av_new = Ave[c * PP + tid] * (1.f - w) + ave * w;

    float ss = av_new * av_new;
    for (int off = 32; off > 0; off >>= 1) ss += __shfl_down(ss, off);
    if ((tid & 63) == 0) red4[tid >> 6] = ss;
    __syncthreads();
    float tot = red4[0] + red4[1] + red4[2] + red4[3];

    float R = sqrtf(tot);
    float kf = 256.0f * R / (1.0f - R * R);
    if (kf > 1e5f || kf < 0.0f) kf = 1e5f;   // matches reference clamp
    float mu = av_new / fmaxf(R, 1e-12f);
    float tv = kf * mu;                      // f32 rounding matches reference temp
    tempT[tid * CC + c] = tv;

    double ts = (double)tv * (double)tv;
    for (int off = 32; off > 0; off >>= 1) ts += __shfl_down(ts, off);
    if ((tid & 63) == 0) redd[tid >> 6] = ts;
    __syncthreads();

    if (tid == 0) {
        kappa_out[c] = kf;
        T2[c] = redd[0] + redd[1] + redd[2] + redd[3];
        // f32 Miller chain (self-damping: ~1e-5 abs error on log terms)
        float invf = 1.0f / kf;
        float In = 1.f, In1 = 0.f, i2 = 508.f;
        for (int it = 0; it < ORD; ++it) {   // i = 254 .. 128
            float t = fmaf(i2 * invf, In, In1);
            In1 = In; In = t; i2 -= 2.f;
        }
        float E0 = In;
        for (int it = 0; it < ORD; ++it) {   // i = 127 .. 1
            float t = fmaf(i2 * invf, In, In1);
            In1 = In; In = t; i2 -= 2.f;
        }
        float x = 0.125f * invf;
        float pser = x * (1.f + x * (4.5f + x * (37.5f + x * 459.375f)));
        float l1p = pser - 0.5f * pser * pser;        // log1p, p ~ 1e-4
        float lr = logf(E0 / In);
        float lk = logf(kf);
        // logc = l1p + lr - 0.5*log(2*pi) + kappa - 127.5*log(kappa)
        logc[c] = (double)(l1p + lr) - 0.9189385332046727
                  + (double)kf - 127.5 * (double)lk;
    }
}

// Kernel C: main. grid (4 c-tiles, 128 n-tiles of 4). Per thread: one c, 4 n's.
// Phase 1: f32 cross-dot (LDS-broadcast f, coalesced tempT).
// Phase 2: k = sqrt(T2 + 2D + F2) f64->f32-rounded; 4 interleaved f32 Miller
// chains; f32 transcendentals; f64 final assembly (k ~ 1e5 cancels vs logc).
__global__ __launch_bounds__(256) void k_main(
    const float* __restrict__ feats, const float* __restrict__ tempT,
    const double* __restrict__ T2, const double* __restrict__ F2,
    const double* __restrict__ logc, float* __restrict__ logits)
{
    __shared__ float f_s[4][PP];
    const int tid = threadIdx.x;
    const int n0  = blockIdx.y * 4;
    const int c   = blockIdx.x * 256 + tid;
    #pragma unroll
    for (int j = 0; j < 4; ++j)
        f_s[j][tid] = feats[(n0 + j) * PP + tid];
    __syncthreads();
    const bool act = (c < CC);

    float a0 = 0.f, a1 = 0.f, a2 = 0.f, a3 = 0.f;
    if (act) {
        #pragma unroll 4
        for (int a = 0; a < PP; ++a) {
            float tv = tempT[a * CC + c];
            a0 = fmaf(tv, f_s[0][a], a0);
            a1 = fmaf(tv, f_s[1][a], a1);
            a2 = fmaf(tv, f_s[2][a], a2);
            a3 = fmaf(tv, f_s[3][a], a3);
        }
    }
    float accs[4] = {a0, a1, a2, a3};
    double t2c = act ? T2[c] : 1.0e6;
    double kd[4];
    float kf[4], invf[4], In[4], In1[4], E0[4];
    #pragma unroll
    for (int j = 0; j < 4; ++j) {
        double kk = act ? (t2c + 2.0 * (double)accs[j] + F2[n0 + j]) : 1.0e6;
        kd[j]  = (double)(float)sqrt(kk);   // f32-round like reference kappa_new
        kf[j]  = (float)kd[j];
        invf[j] = 1.0f / kf[j];
        In[j] = 1.f; In1[j] = 0.f;
    }
    float i2 = 508.f;                       // exact f32 integer arithmetic
    for (int it = 0; it < ORD; ++it) {      // i = 254 .. 128
        #pragma unroll
        for (int j = 0; j < 4; ++j) {
            float t = fmaf(i2 * invf[j], In[j], In1[j]);
            In1[j] = In[j]; In[j] = t;
        }
        i2 -= 2.f;
    }
    #pragma unroll
    for (int j = 0; j < 4; ++j) E0[j] = In[j];
    for (int it = 0; it < ORD; ++it) {      // i = 127 .. 1
        #pragma unroll
        for (int j = 0; j < 4; ++j) {
            float t = fmaf(i2 * invf[j], In[j], In1[j]);
            In1[j] = In[j]; In[j] = t;
        }
        i2 -= 2.f;
    }
    if (!act) return;
    double lgc = logc[c];
    #pragma unroll
    for (int j = 0; j < 4; ++j) {
        float x = 0.125f * invf[j];
        float pser = x * (1.f + x * (4.5f + x * (37.5f + x * 459.375f)));
        float l1p = pser - 0.5f * pser * pser;
        float lr = logf(E0[j] / In[j]);
        float lk = logf(kf[j]);
        double lg = (double)(l1p + lr) - 0.9189385332046727
                    + kd[j] - 127.5 * (double)lk - lgc;
        logits[(n0 + j) * CC + c] = (float)lg;
    }
}

// Kernel D: row-normalize -> f32 output
__global__ __launch_bounds__(256) void k_norm(
    const float* __restrict__ logits, float* __restrict__ out)
{
    __shared__ double red4[4];
    const int n = blockIdx.x;
    const int tid = threadIdx.x;
    float v[4];
    double ss = 0.0;
    #pragma unroll
    for (int q = 0; q < 4; ++q) {
        int c = tid + q * 256;
        v[q] = (c < CC) ? logits[n * CC + c] : 0.f;
        ss += (double)v[q] * (double)v[q];
    }
    for (int off = 32; off > 0; off >>= 1) ss += __shfl_down(ss, off);
    if ((tid & 63) == 0) red4[tid >> 6] = ss;
    __syncthreads();
    double tot = red4[0] + red4[1] + red4[2] + red4[3];
    float inv = 1.0f / fmaxf((float)sqrt(tot), 1e-12f);
    #pragma unroll
    for (int q = 0; q < 4; ++q) {
        int c = tid + q * 256;
        if (c < CC) out[n * CC + c] = v[q] * inv;
    }
}

extern "C" void kernel_launch(void* const* d_in, const int* in_sizes, int n_in,
                              void* d_out, int out_size, void* d_ws, size_t ws_size,
                              hipStream_t stream) {
    int i_feat = -1, i_ave = -1, i_amt = -1, i5a = -1, i5b = -1;
    for (int i = 0; i < n_in; ++i) {
        int s = in_sizes[i];
        if      (s == NN * PP) i_feat = i;
        else if (s == CC * PP) i_ave  = i;
        else if (s == CC)      i_amt  = i;
        else if (s == NN)      { if (i5a < 0) i5a = i; else i5b = i; }
    }
    if (i_feat < 0 || i_ave < 0 || i_amt < 0 || i5a < 0 || i5b < 0) {
        i_feat = 0; i5a = 1; i5b = 2; i_ave = 3; i_amt = 4;  // documented order
    }
    const float*    feats  = (const float*)d_in[i_feat];
    const unsigned* bufA   = (const unsigned*)d_in[i5a];
    const unsigned* bufB   = (const unsigned*)d_in[i5b];
    const float*    Ave    = (const float*)d_in[i_ave];
    const float*    Amount = (const float*)d_in[i_amt];

    char* ws = (char*)d_ws;
    float*  tempT  = (float*)(ws + OFF_TEMPT);
    float*  kappa  = (float*)(ws + OFF_KAPPA);
    double* logc   = (double*)(ws + OFF_LOGC);
    double* T2     = (double*)(ws + OFF_T2);
    double* F2     = (double*)(ws + OFF_F2);
    float*  logits = (float*)(ws + OFF_LOGITS);
    float*  accum  = (float*)(ws + OFF_ACCUM);   // aliases logits (dead then)
    int*    cnt    = (int*)(ws + OFF_CNT);
    float*  out    = (float*)d_out;

    // zero accum + cnt (graph-capturable async memset replaces k_zero)
    hipMemsetAsync(ws + OFF_ACCUM, 0, (size_t)CC * PP * 4 + (size_t)CC * 4, stream);
    k_scatter<<<dim3(NN), dim3(256), 0, stream>>>(feats, bufA, bufB, accum, cnt, F2);
    k_class<<<dim3(CC), dim3(256), 0, stream>>>(accum, cnt, Ave, Amount,
                                                tempT, kappa, T2, logc);
    k_main<<<dim3(4, NN / 4), dim3(256), 0, stream>>>(feats, tempT, T2, F2,
                                                      logc, logits);
    k_norm<<<dim3(NN), dim3(256), 0, stream>>>(logits, out);
}